// Round 7
// baseline (211.470 us; speedup 1.0000x reference)
//
#include <hip/hip_runtime.h>
#include <hip/hip_bf16.h>
#include <cmath>

#define D_MODEL 1024
#define NHEADS 16
#define HDIM 64
#define BATCH 2
#define SEQ 2048
#define MROWS (BATCH*SEQ)   // 4096
#define KDIM 1024

typedef unsigned short ushort_t;
typedef unsigned int uint32;
typedef __attribute__((ext_vector_type(8))) short short8;
typedef __attribute__((ext_vector_type(4))) float floatx4;

#define QSCALE 0.1803368801111204f   /* 0.125 * log2(e): scores land in exp2 domain */
#define EXP2F(x) __builtin_amdgcn_exp2f(x)

__device__ __forceinline__ ushort_t f2bf(float x) {
    union { float f; uint32 u; } v; v.f = x;
    uint32 r = v.u + 0x7FFFu + ((v.u >> 16) & 1u);
    return (ushort_t)(r >> 16);
}

__device__ __forceinline__ uint32 pkbf(float a, float b) {
    union { __hip_bfloat162 h2; uint32 u; } v;
    v.h2 = __float22bfloat162_rn(make_float2(a, b));
    return v.u;
}

__device__ __forceinline__ void glds16(const void* g, void* l) {
    __builtin_amdgcn_global_load_lds(
        (const __attribute__((address_space(1))) void*)g,
        (__attribute__((address_space(3))) void*)l, 16, 0, 0);
}

// ---------------- fused conversions: z<4 -> W transpose, z==4 -> x cvt ----------------
__global__ __launch_bounds__(256)
void cvt_all(const float* __restrict__ x, const float* __restrict__ W0,
             const float* __restrict__ W1, const float* __restrict__ W2,
             const float* __restrict__ W3, ushort_t* __restrict__ xb,
             ushort_t* __restrict__ WtQKV, ushort_t* __restrict__ WtO)
{
    const int z = blockIdx.z;
    if (z == 4) {
        // x fp32 -> bf16: 262144 threads in this slice, 4 float4 per thread
        size_t idx = ((size_t)blockIdx.y * 32 + blockIdx.x) * 256 + threadIdx.x;
        #pragma unroll
        for (int l = 0; l < 4; ++l) {
            size_t i = ((size_t)l * 262144 + idx) * 4;   // float4 index * 4 elems
            float4 v = *(const float4*)(x + i);
            uint2 o;
            o.x = pkbf(v.x, v.y);
            o.y = pkbf(v.z, v.w);
            *(uint2*)(xb + i) = o;
        }
        return;
    }
    __shared__ float tl[32][33];
    const float* W = (z == 0) ? W0 : (z == 1) ? W1 : (z == 2) ? W2 : W3;
    ushort_t* out = (z < 3) ? (WtQKV + (size_t)z * D_MODEL * KDIM) : WtO;
    const int k0 = blockIdx.x * 32, n0 = blockIdx.y * 32;
    const int tx = threadIdx.x & 31, ty = threadIdx.x >> 5;
    #pragma unroll
    for (int i = 0; i < 4; ++i)
        tl[ty + i * 8][tx] = W[(size_t)(k0 + ty + i * 8) * D_MODEL + n0 + tx];
    __syncthreads();
    #pragma unroll
    for (int i = 0; i < 4; ++i)
        out[(size_t)(n0 + ty + i * 8) * KDIM + k0 + tx] = f2bf(tl[tx][ty + i * 8]);
}

// ---------------- bf16 MFMA GEMM: C = A[4096,K] * Bt^T + bias ----------------
// Block tile 128 x BN, BK=64, 4 waves, 16x16x32 MFMA, XOR-swizzled glds staging.
// mode 0: fp32 C[m][n] (+bias).  mode 1 (BN=128): QKV epilogue:
//   Q -> bf16 [b,h,s,d] * QSCALE; K -> bf16 [b,h,s,d]; V -> bf16 [b,h,d,s].
template<int BN>
__global__ __launch_bounds__(256)
void gemm_mfma(const ushort_t* __restrict__ A, const ushort_t* __restrict__ Bt,
               const float* __restrict__ b0, const float* __restrict__ b1,
               const float* __restrict__ b2, float* __restrict__ Cf,
               ushort_t* __restrict__ Qb, ushort_t* __restrict__ Kb,
               ushort_t* __restrict__ Vb, int mode)
{
    constexpr int NT = BN / 32;          // n-blocks per wave
    constexpr int BC = BN / 32;          // B staging chunks per thread
    __shared__ ushort_t As[128 * 64];
    __shared__ ushort_t Bs[BN * 64];

    const int tid = threadIdx.x;
    const int w = tid >> 6, lane = tid & 63;
    const int quad = lane >> 4, col = lane & 15;
    const int m0 = blockIdx.y * 128, n0 = blockIdx.x * BN;
    const int mbase = (w & 1) * 64, nbase = (w >> 1) * (BN / 2);

    floatx4 zero = {0.f, 0.f, 0.f, 0.f};
    floatx4 acc[4][NT];
    #pragma unroll
    for (int i = 0; i < 4; ++i)
        #pragma unroll
        for (int j = 0; j < NT; ++j) acc[i][j] = zero;

    #pragma unroll 1
    for (int k0 = 0; k0 < KDIM; k0 += 64) {
        #pragma unroll
        for (int i = 0; i < 4; ++i) {
            int c = (w * 4 + i) * 64 + lane;
            int row = c >> 3;
            int kc = (c & 7) ^ (row & 7);
            glds16(A + (size_t)(m0 + row) * KDIM + k0 + kc * 8, As + (w * 4 + i) * 512);
        }
        #pragma unroll
        for (int i = 0; i < BC; ++i) {
            int c = (w * BC + i) * 64 + lane;
            int row = c >> 3;
            int kc = (c & 7) ^ (row & 7);
            glds16(Bt + (size_t)(n0 + row) * KDIM + k0 + kc * 8, Bs + (w * BC + i) * 512);
        }
        __syncthreads();
        #pragma unroll
        for (int ks = 0; ks < 2; ++ks) {
            short8 af[4], bfr[NT];
            const int kc = ks * 4 + quad;
            #pragma unroll
            for (int mt = 0; mt < 4; ++mt) {
                int r = mbase + mt * 16 + col;
                af[mt] = *(const short8*)(As + ((size_t)r * 8 + (kc ^ (r & 7))) * 8);
            }
            #pragma unroll
            for (int nt = 0; nt < NT; ++nt) {
                int r = nbase + nt * 16 + col;
                bfr[nt] = *(const short8*)(Bs + ((size_t)r * 8 + (kc ^ (r & 7))) * 8);
            }
            #pragma unroll
            for (int mt = 0; mt < 4; ++mt)
                #pragma unroll
                for (int nt = 0; nt < NT; ++nt)
                    acc[mt][nt] = __builtin_amdgcn_mfma_f32_16x16x32_bf16(
                        af[mt], bfr[nt], acc[mt][nt], 0, 0, 0);
        }
        __syncthreads();
    }

    if (mode == 0) {
        #pragma unroll
        for (int mt = 0; mt < 4; ++mt)
            #pragma unroll
            for (int nt = 0; nt < NT; ++nt) {
                int n = n0 + nbase + nt * 16 + col;
                float bb = b0[n];
                #pragma unroll
                for (int r = 0; r < 4; ++r) {
                    int m = m0 + mbase + mt * 16 + quad * 4 + r;
                    Cf[(size_t)m * D_MODEL + n] = acc[mt][nt][r] + bb;
                }
            }
    } else {
        const int which = n0 >> 10;
        const float* bp = (which == 0) ? b0 : (which == 1) ? b1 : b2;
        if (which < 2) {
            ushort_t* outp = (which == 0) ? Qb : Kb;
            const float scl = (which == 0) ? QSCALE : 1.0f;
            #pragma unroll
            for (int mt = 0; mt < 4; ++mt)
                #pragma unroll
                for (int nt = 0; nt < NT; ++nt) {
                    int nn = (n0 + nbase + nt * 16 + col) & 1023;
                    float bb = bp[nn];
                    int h = nn >> 6, d = nn & 63;
                    #pragma unroll
                    for (int r = 0; r < 4; ++r) {
                        int m = m0 + mbase + mt * 16 + quad * 4 + r;
                        int b = m >> 11, s = m & 2047;
                        outp[((size_t)(b * NHEADS + h) * SEQ + s) * HDIM + d] =
                            f2bf((acc[mt][nt][r] + bb) * scl);
                    }
                }
        } else {
            // V -> [b,h,d,s] transposed, packed 8B stores
            #pragma unroll
            for (int mt = 0; mt < 4; ++mt)
                #pragma unroll
                for (int nt = 0; nt < NT; ++nt) {
                    int nn = (n0 + nbase + nt * 16 + col) & 1023;
                    float bb = bp[nn];
                    int h = nn >> 6, d = nn & 63;
                    int mb = m0 + mbase + mt * 16 + quad * 4;
                    int b = mb >> 11, s = mb & 2047;
                    uint2 pw;
                    pw.x = pkbf(acc[mt][nt][0] + bb, acc[mt][nt][1] + bb);
                    pw.y = pkbf(acc[mt][nt][2] + bb, acc[mt][nt][3] + bb);
                    *(uint2*)(Vb + ((size_t)(b * NHEADS + h) * HDIM + d) * SEQ + s) = pw;
                }
        }
    }
}

// ---------------- flash causal attention v4 ----------------
// 1024 blocks x 2 waves (32 q-rows each, wave w owns rows [w*16,w*16+16)).
// Pair-balanced over 64 32-row q-tiles: block handles (63-x, x) -> ~33 uniform
// k-steps. XCD-aware decode: blk&7 selects a 4-bh group so each XCD's L2 only
// holds 2 MB of K/V. glds staging (2 barriers/step); 4 independent blocks/CU
// hide each other's barrier drains. S^T = K.Q^T scheme; Ps per-wave in LDS.
__global__ __launch_bounds__(128)
void attn_mfma(const ushort_t* __restrict__ Q, const ushort_t* __restrict__ K,
               const ushort_t* __restrict__ Vt, ushort_t* __restrict__ H)
{
    __shared__ ushort_t Ks[64 * 64];   // 8 KB
    __shared__ ushort_t Vs[64 * 64];   // 8 KB
    __shared__ ushort_t Ps[32 * 64];   // 4 KB

    const int tid = threadIdx.x;
    const int w = tid >> 6, lane = tid & 63;
    const int quad = lane >> 4, col = lane & 15;
    const int blk = blockIdx.x;                       // 0..1023
    const int bh = (blk & 7) * 4 + ((blk >> 3) & 3);  // XCD-grouped
    const int pair = blk >> 5;                        // 0..31
    const size_t base = (size_t)bh * SEQ * HDIM;
    const ushort_t* Kb = K + base;
    const ushort_t* Vb = Vt + base;
    const int b = bh >> 4, h = bh & 15;
    const int qrow = w * 16 + col;                    // local q row / Ps row

    // staging geometry: 4 K-chunks + 4 V-chunks per thread (512 chunks/tile)
    int srow[4], soff[4];
    #pragma unroll
    for (int i = 0; i < 4; ++i) {
        int c = i * 128 + tid;
        srow[i] = c >> 3;
        soff[i] = ((c & 7) ^ ((c >> 3) & 7)) * 8;
    }

    const floatx4 zero = {0.f, 0.f, 0.f, 0.f};

    #pragma unroll 1
    for (int pi = 0; pi < 2; ++pi) {
        const int qt = pi ? pair : 63 - pair;
        const int q0 = qt * 32;
        const int nt = (qt >> 1) + 1;

        // Q B-frags straight from global (per-lane 16B loads)
        short8 bq[2];
        bq[0] = *(const short8*)(Q + base + (size_t)(q0 + qrow) * HDIM + quad * 8);
        bq[1] = *(const short8*)(Q + base + (size_t)(q0 + qrow) * HDIM + 32 + quad * 8);

        floatx4 o[4];
        #pragma unroll
        for (int j = 0; j < 4; ++j) o[j] = zero;
        float mreg = -INFINITY, lreg = 0.f;

        #pragma unroll 1
        for (int t = 0; t < nt; ++t) {
            const int k0 = t * 64;
            __syncthreads();          // all waves done reading Ks/Vs
            #pragma unroll
            for (int i = 0; i < 4; ++i) {
                const int cb = i * 128 + w * 64;      // wave-uniform LDS chunk base
                glds16(Kb + (size_t)(k0 + srow[i]) * HDIM + soff[i], Ks + (size_t)cb * 8);
                glds16(Vb + (size_t)srow[i] * SEQ + k0 + soff[i],    Vs + (size_t)cb * 8);
            }
            __syncthreads();          // staged tile visible

            // S^T[kpos][q]: sc[j] reg r -> kpos = j*16+quad*4+r, q = col
            floatx4 sc[4];
            #pragma unroll
            for (int j = 0; j < 4; ++j) sc[j] = zero;
            #pragma unroll
            for (int ks = 0; ks < 2; ++ks) {
                const int kc = ks * 4 + quad;
                #pragma unroll
                for (int j = 0; j < 4; ++j) {
                    int rk = j * 16 + col;
                    short8 ak = *(const short8*)(Ks + ((size_t)rk * 8 + (kc ^ (rk & 7))) * 8);
                    sc[j] = __builtin_amdgcn_mfma_f32_16x16x32_bf16(ak, bq[ks], sc[j], 0, 0, 0);
                }
            }

            // causal mask on last k-tile (q-tile is 32 rows, k-tile 64 cols)
            if (t == nt - 1) {
                const int qg = q0 + qrow - k0;        // 0..63
                #pragma unroll
                for (int j = 0; j < 4; ++j)
                    #pragma unroll
                    for (int r = 0; r < 4; ++r)
                        if (j * 16 + quad * 4 + r > qg) sc[j][r] = -INFINITY;
            }

            // online softmax: 15 local ops + 2 shfls per lane
            float mx = -INFINITY;
            #pragma unroll
            for (int j = 0; j < 4; ++j)
                mx = fmaxf(mx, fmaxf(fmaxf(sc[j][0], sc[j][1]), fmaxf(sc[j][2], sc[j][3])));
            mx = fmaxf(mx, __shfl_xor(mx, 16));
            mx = fmaxf(mx, __shfl_xor(mx, 32));
            float mn = fmaxf(mreg, mx);
            float alpha = EXP2F(mreg - mn);
            mreg = mn;

            float ls = 0.f;
            #pragma unroll
            for (int j = 0; j < 4; ++j) {
                float p0 = EXP2F(sc[j][0] - mn);
                float p1 = EXP2F(sc[j][1] - mn);
                float p2 = EXP2F(sc[j][2] - mn);
                float p3 = EXP2F(sc[j][3] - mn);
                ls += (p0 + p1) + (p2 + p3);
                uint2 pw;
                pw.x = pkbf(p0, p1);
                pw.y = pkbf(p2, p3);
                int c = 2 * j + (quad >> 1);
                *(uint2*)(Ps + ((size_t)qrow * 8 + (c ^ (qrow & 7))) * 8 + (quad & 1) * 4) = pw;
            }
            ls += __shfl_xor(ls, 16);
            ls += __shfl_xor(ls, 32);
            lreg = lreg * alpha + ls;
            #pragma unroll
            for (int j = 0; j < 4; ++j) {
                o[j][0] *= alpha; o[j][1] *= alpha; o[j][2] *= alpha; o[j][3] *= alpha;
            }

            // O^T += V^T . P^T : A = Vs (rows=d), B = Ps (rows=q, own wave)
            #pragma unroll
            for (int ks = 0; ks < 2; ++ks) {
                const int kc = ks * 4 + quad;
                short8 bp = *(const short8*)(Ps + ((size_t)qrow * 8 + (kc ^ (qrow & 7))) * 8);
                #pragma unroll
                for (int j = 0; j < 4; ++j) {
                    int rv = j * 16 + col;
                    short8 av = *(const short8*)(Vs + ((size_t)rv * 8 + (kc ^ (rv & 7))) * 8);
                    o[j] = __builtin_amdgcn_mfma_f32_16x16x32_bf16(av, bp, o[j], 0, 0, 0);
                }
            }
        }

        // epilogue: lane owns q row s = q0+qrow, d = j*16+quad*4+r
        const float linv = 1.f / lreg;
        const size_t rowb = ((size_t)(b * SEQ + q0 + qrow)) * D_MODEL + h * HDIM;
        #pragma unroll
        for (int j = 0; j < 4; ++j) {
            uint2 pw;
            pw.x = pkbf(o[j][0] * linv, o[j][1] * linv);
            pw.y = pkbf(o[j][2] * linv, o[j][3] * linv);
            *(uint2*)(H + rowb + j * 16 + quad * 4) = pw;
        }
    }
}

extern "C" void kernel_launch(void* const* d_in, const int* in_sizes, int n_in,
                              void* d_out, int out_size, void* d_ws, size_t ws_size,
                              hipStream_t stream)
{
    (void)in_sizes; (void)n_in; (void)out_size; (void)ws_size;
    const float* x  = (const float*)d_in[0];
    const float* Wq = (const float*)d_in[1];
    const float* bq = (const float*)d_in[2];
    const float* Wk = (const float*)d_in[3];
    const float* bk = (const float*)d_in[4];
    const float* Wv = (const float*)d_in[5];
    const float* bv = (const float*)d_in[6];
    const float* Wo = (const float*)d_in[7];
    const float* bo = (const float*)d_in[8];

    const size_t E = (size_t)MROWS * D_MODEL;
    ushort_t* xb    = (ushort_t*)d_ws;               // [4096][1024] bf16
    ushort_t* WtQKV = xb + E;                        // [3072][1024] bf16
    ushort_t* WtO   = WtQKV + 3 * (size_t)D_MODEL * KDIM;
    ushort_t* Qb    = WtO + (size_t)D_MODEL * KDIM;  // [b,h,s,d] bf16 (pre-scaled)
    ushort_t* Kb    = Qb + E;                        // [b,h,s,d] bf16
    ushort_t* Vb    = Kb + E;                        // [b,h,d,s] bf16 (transposed)
    ushort_t* Hb    = Vb + E;                        // [4096][1024] bf16

    cvt_all<<<dim3(32, 32, 5), 256, 0, stream>>>(x, Wq, Wk, Wv, Wo, xb, WtQKV, WtO);
    gemm_mfma<128><<<dim3(24, 32), 256, 0, stream>>>(xb, WtQKV, bq, bk, bv,
                                                     nullptr, Qb, Kb, Vb, 1);
    attn_mfma<<<dim3(1024), 128, 0, stream>>>(Qb, Kb, Vb, Hb);
    gemm_mfma<64><<<dim3(16, 32), 256, 0, stream>>>(Hb, WtO, bo, nullptr, nullptr,
                                                    (float*)d_out, nullptr, nullptr, nullptr, 0);
}

// Round 8
// 210.455 us; speedup vs baseline: 1.0048x; 1.0048x over previous
//
#include <hip/hip_runtime.h>
#include <hip/hip_bf16.h>
#include <cmath>

#define D_MODEL 1024
#define NHEADS 16
#define HDIM 64
#define BATCH 2
#define SEQ 2048
#define MROWS (BATCH*SEQ)   // 4096
#define KDIM 1024

typedef unsigned short ushort_t;
typedef unsigned int uint32;
typedef __attribute__((ext_vector_type(8))) short short8;
typedef __attribute__((ext_vector_type(4))) float floatx4;

#define QSCALE 0.1803368801111204f   /* 0.125 * log2(e): scores land in exp2 domain */
#define EXP2F(x) __builtin_amdgcn_exp2f(x)

__device__ __forceinline__ ushort_t f2bf(float x) {
    union { float f; uint32 u; } v; v.f = x;
    uint32 r = v.u + 0x7FFFu + ((v.u >> 16) & 1u);
    return (ushort_t)(r >> 16);
}

__device__ __forceinline__ uint32 pkbf(float a, float b) {
    union { __hip_bfloat162 h2; uint32 u; } v;
    v.h2 = __float22bfloat162_rn(make_float2(a, b));
    return v.u;
}

__device__ __forceinline__ void glds16(const void* g, void* l) {
    __builtin_amdgcn_global_load_lds(
        (const __attribute__((address_space(1))) void*)g,
        (__attribute__((address_space(3))) void*)l, 16, 0, 0);
}

// ---------------- fused conversions: z<4 -> W transpose, z==4 -> x cvt ----------------
__global__ __launch_bounds__(256)
void cvt_all(const float* __restrict__ x, const float* __restrict__ W0,
             const float* __restrict__ W1, const float* __restrict__ W2,
             const float* __restrict__ W3, ushort_t* __restrict__ xb,
             ushort_t* __restrict__ WtQKV, ushort_t* __restrict__ WtO)
{
    const int z = blockIdx.z;
    if (z == 4) {
        // x fp32 -> bf16: 262144 threads in this slice, 4 float4 per thread
        size_t idx = ((size_t)blockIdx.y * 32 + blockIdx.x) * 256 + threadIdx.x;
        #pragma unroll
        for (int l = 0; l < 4; ++l) {
            size_t i = ((size_t)l * 262144 + idx) * 4;   // float4 index * 4 elems
            float4 v = *(const float4*)(x + i);
            uint2 o;
            o.x = pkbf(v.x, v.y);
            o.y = pkbf(v.z, v.w);
            *(uint2*)(xb + i) = o;
        }
        return;
    }
    __shared__ float tl[32][33];
    const float* W = (z == 0) ? W0 : (z == 1) ? W1 : (z == 2) ? W2 : W3;
    ushort_t* out = (z < 3) ? (WtQKV + (size_t)z * D_MODEL * KDIM) : WtO;
    const int k0 = blockIdx.x * 32, n0 = blockIdx.y * 32;
    const int tx = threadIdx.x & 31, ty = threadIdx.x >> 5;
    #pragma unroll
    for (int i = 0; i < 4; ++i)
        tl[ty + i * 8][tx] = W[(size_t)(k0 + ty + i * 8) * D_MODEL + n0 + tx];
    __syncthreads();
    #pragma unroll
    for (int i = 0; i < 4; ++i)
        out[(size_t)(n0 + ty + i * 8) * KDIM + k0 + tx] = f2bf(tl[tx][ty + i * 8]);
}

// ---------------- bf16 MFMA GEMM: C = A[4096,K] * Bt^T + bias ----------------
template<int BN>
__global__ __launch_bounds__(256)
void gemm_mfma(const ushort_t* __restrict__ A, const ushort_t* __restrict__ Bt,
               const float* __restrict__ b0, const float* __restrict__ b1,
               const float* __restrict__ b2, float* __restrict__ Cf,
               ushort_t* __restrict__ Qb, ushort_t* __restrict__ Kb,
               ushort_t* __restrict__ Vb, int mode)
{
    constexpr int NT = BN / 32;          // n-blocks per wave
    constexpr int BC = BN / 32;          // B staging chunks per thread
    __shared__ ushort_t As[128 * 64];
    __shared__ ushort_t Bs[BN * 64];

    const int tid = threadIdx.x;
    const int w = tid >> 6, lane = tid & 63;
    const int quad = lane >> 4, col = lane & 15;
    const int m0 = blockIdx.y * 128, n0 = blockIdx.x * BN;
    const int mbase = (w & 1) * 64, nbase = (w >> 1) * (BN / 2);

    floatx4 zero = {0.f, 0.f, 0.f, 0.f};
    floatx4 acc[4][NT];
    #pragma unroll
    for (int i = 0; i < 4; ++i)
        #pragma unroll
        for (int j = 0; j < NT; ++j) acc[i][j] = zero;

    #pragma unroll 1
    for (int k0 = 0; k0 < KDIM; k0 += 64) {
        #pragma unroll
        for (int i = 0; i < 4; ++i) {
            int c = (w * 4 + i) * 64 + lane;
            int row = c >> 3;
            int kc = (c & 7) ^ (row & 7);
            glds16(A + (size_t)(m0 + row) * KDIM + k0 + kc * 8, As + (w * 4 + i) * 512);
        }
        #pragma unroll
        for (int i = 0; i < BC; ++i) {
            int c = (w * BC + i) * 64 + lane;
            int row = c >> 3;
            int kc = (c & 7) ^ (row & 7);
            glds16(Bt + (size_t)(n0 + row) * KDIM + k0 + kc * 8, Bs + (w * BC + i) * 512);
        }
        __syncthreads();
        #pragma unroll
        for (int ks = 0; ks < 2; ++ks) {
            short8 af[4], bfr[NT];
            const int kc = ks * 4 + quad;
            #pragma unroll
            for (int mt = 0; mt < 4; ++mt) {
                int r = mbase + mt * 16 + col;
                af[mt] = *(const short8*)(As + ((size_t)r * 8 + (kc ^ (r & 7))) * 8);
            }
            #pragma unroll
            for (int nt = 0; nt < NT; ++nt) {
                int r = nbase + nt * 16 + col;
                bfr[nt] = *(const short8*)(Bs + ((size_t)r * 8 + (kc ^ (r & 7))) * 8);
            }
            #pragma unroll
            for (int mt = 0; mt < 4; ++mt)
                #pragma unroll
                for (int nt = 0; nt < NT; ++nt)
                    acc[mt][nt] = __builtin_amdgcn_mfma_f32_16x16x32_bf16(
                        af[mt], bfr[nt], acc[mt][nt], 0, 0, 0);
        }
        __syncthreads();
    }

    if (mode == 0) {
        #pragma unroll
        for (int mt = 0; mt < 4; ++mt)
            #pragma unroll
            for (int nt = 0; nt < NT; ++nt) {
                int n = n0 + nbase + nt * 16 + col;
                float bb = b0[n];
                #pragma unroll
                for (int r = 0; r < 4; ++r) {
                    int m = m0 + mbase + mt * 16 + quad * 4 + r;
                    Cf[(size_t)m * D_MODEL + n] = acc[mt][nt][r] + bb;
                }
            }
    } else {
        const int which = n0 >> 10;
        const float* bp = (which == 0) ? b0 : (which == 1) ? b1 : b2;
        if (which < 2) {
            ushort_t* outp = (which == 0) ? Qb : Kb;
            const float scl = (which == 0) ? QSCALE : 1.0f;
            #pragma unroll
            for (int mt = 0; mt < 4; ++mt)
                #pragma unroll
                for (int nt = 0; nt < NT; ++nt) {
                    int nn = (n0 + nbase + nt * 16 + col) & 1023;
                    float bb = bp[nn];
                    int h = nn >> 6, d = nn & 63;
                    #pragma unroll
                    for (int r = 0; r < 4; ++r) {
                        int m = m0 + mbase + mt * 16 + quad * 4 + r;
                        int b = m >> 11, s = m & 2047;
                        outp[((size_t)(b * NHEADS + h) * SEQ + s) * HDIM + d] =
                            f2bf((acc[mt][nt][r] + bb) * scl);
                    }
                }
        } else {
            // V -> [b,h,d,s] transposed, packed 8B stores
            #pragma unroll
            for (int mt = 0; mt < 4; ++mt)
                #pragma unroll
                for (int nt = 0; nt < NT; ++nt) {
                    int nn = (n0 + nbase + nt * 16 + col) & 1023;
                    float bb = bp[nn];
                    int h = nn >> 6, d = nn & 63;
                    int mb = m0 + mbase + mt * 16 + quad * 4;
                    int b = mb >> 11, s = mb & 2047;
                    uint2 pw;
                    pw.x = pkbf(acc[mt][nt][0] + bb, acc[mt][nt][1] + bb);
                    pw.y = pkbf(acc[mt][nt][2] + bb, acc[mt][nt][3] + bb);
                    *(uint2*)(Vb + ((size_t)(b * NHEADS + h) * HDIM + d) * SEQ + s) = pw;
                }
        }
    }
}

// ---------------- flash causal attention v5 ----------------
// 1024 blocks x 2 waves; each block one 64-row q-tile; wave owns 32 q-COLS
// (two 16-col groups) so every Ks/Vs A-frag read feeds 2 MFMAs (LDS
// reads/MFMA: 1.125 -> 0.625 b128). 4 blocks/CU hide barriers. qt decode:
// the 4 blocks of a blk%256 cohort sum to 62 k-steps (load balance);
// bh XCD-grouped (blk&7) so K/V live in one XCD's L2.
__global__ __launch_bounds__(128)
void attn_mfma(const ushort_t* __restrict__ Q, const ushort_t* __restrict__ K,
               const ushort_t* __restrict__ Vt, ushort_t* __restrict__ H)
{
    __shared__ ushort_t Ks[64 * 64];   // 8 KB
    __shared__ ushort_t Vs[64 * 64];   // 8 KB
    __shared__ ushort_t Ps[64 * 64];   // 8 KB (2 waves x 32 q-rows)

    const int tid = threadIdx.x;
    const int w = tid >> 6, lane = tid & 63;
    const int quad = lane >> 4, col = lane & 15;
    const int blk = blockIdx.x;                       // 0..1023
    const int bh = (blk & 7) * 4 + ((blk >> 3) & 3);  // XCD-grouped
    const int g = blk >> 5;                           // 0..31
    const int qt = (g < 8) ? 31 - g : (g < 16) ? g : (g < 24) ? 39 - g : g - 24;
    const int q0 = qt * 64;
    const int nt = qt + 1;
    const size_t base = (size_t)bh * SEQ * HDIM;
    const ushort_t* Kb = K + base;
    const ushort_t* Vb = Vt + base;
    const int b = bh >> 4, h = bh & 15;

    // staging geometry: 4 K-chunks + 4 V-chunks per thread (512+512 chunks/tile)
    int srow[4], soff[4];
    #pragma unroll
    for (int i = 0; i < 4; ++i) {
        int c = i * 128 + tid;
        srow[i] = c >> 3;
        soff[i] = ((c & 7) ^ ((c >> 3) & 7)) * 8;
    }

    // wave w owns q-cols [w*32, w*32+32): group qg=0,1 -> q row w*32+qg*16+col
    const int rq0 = w * 32 + col;
    const int rq1 = w * 32 + 16 + col;
    short8 bq[2][2];   // [ks][qg]
    #pragma unroll
    for (int qg = 0; qg < 2; ++qg) {
        const ushort_t* qp = Q + base + (size_t)(q0 + w * 32 + qg * 16 + col) * HDIM;
        bq[0][qg] = *(const short8*)(qp + quad * 8);
        bq[1][qg] = *(const short8*)(qp + 32 + quad * 8);
    }

    const floatx4 zero = {0.f, 0.f, 0.f, 0.f};
    floatx4 o[2][4];
    #pragma unroll
    for (int qg = 0; qg < 2; ++qg)
        #pragma unroll
        for (int j = 0; j < 4; ++j) o[qg][j] = zero;
    float mreg[2] = {-INFINITY, -INFINITY};
    float lreg[2] = {0.f, 0.f};

    #pragma unroll 1
    for (int t = 0; t < nt; ++t) {
        const int k0 = t * 64;
        __syncthreads();          // all waves done reading Ks/Vs
        #pragma unroll
        for (int i = 0; i < 4; ++i) {
            const int cb = i * 128 + w * 64;      // wave-uniform LDS chunk base
            glds16(Kb + (size_t)(k0 + srow[i]) * HDIM + soff[i], Ks + (size_t)cb * 8);
            glds16(Vb + (size_t)srow[i] * SEQ + k0 + soff[i],    Vs + (size_t)cb * 8);
        }
        __syncthreads();          // staged tile visible

        // S^T[kpos][q]: sc[qg][j] reg r -> kpos = j*16+quad*4+r, q-group qg
        floatx4 sc[2][4];
        #pragma unroll
        for (int qg = 0; qg < 2; ++qg)
            #pragma unroll
            for (int j = 0; j < 4; ++j) sc[qg][j] = zero;
        #pragma unroll
        for (int ks = 0; ks < 2; ++ks) {
            const int kc = ks * 4 + quad;
            #pragma unroll
            for (int j = 0; j < 4; ++j) {
                int rk = j * 16 + col;
                short8 ak = *(const short8*)(Ks + ((size_t)rk * 8 + (kc ^ (rk & 7))) * 8);
                sc[0][j] = __builtin_amdgcn_mfma_f32_16x16x32_bf16(ak, bq[ks][0], sc[0][j], 0, 0, 0);
                sc[1][j] = __builtin_amdgcn_mfma_f32_16x16x32_bf16(ak, bq[ks][1], sc[1][j], 0, 0, 0);
            }
        }

        // causal mask on the diagonal tile (last k-tile of this q-tile)
        if (t == nt - 1) {
            #pragma unroll
            for (int qg = 0; qg < 2; ++qg) {
                const int qloc = w * 32 + qg * 16 + col;
                #pragma unroll
                for (int j = 0; j < 4; ++j)
                    #pragma unroll
                    for (int r = 0; r < 4; ++r)
                        if (j * 16 + quad * 4 + r > qloc) sc[qg][j][r] = -INFINITY;
            }
        }

        // online softmax per q-group: 15 local ops + 2 shfls
        #pragma unroll
        for (int qg = 0; qg < 2; ++qg) {
            const int rq = qg ? rq1 : rq0;
            float mx = -INFINITY;
            #pragma unroll
            for (int j = 0; j < 4; ++j)
                mx = fmaxf(mx, fmaxf(fmaxf(sc[qg][j][0], sc[qg][j][1]),
                                     fmaxf(sc[qg][j][2], sc[qg][j][3])));
            mx = fmaxf(mx, __shfl_xor(mx, 16));
            mx = fmaxf(mx, __shfl_xor(mx, 32));
            float mn = fmaxf(mreg[qg], mx);
            float alpha = EXP2F(mreg[qg] - mn);
            mreg[qg] = mn;

            float ls = 0.f;
            #pragma unroll
            for (int j = 0; j < 4; ++j) {
                float p0 = EXP2F(sc[qg][j][0] - mn);
                float p1 = EXP2F(sc[qg][j][1] - mn);
                float p2 = EXP2F(sc[qg][j][2] - mn);
                float p3 = EXP2F(sc[qg][j][3] - mn);
                ls += (p0 + p1) + (p2 + p3);
                uint2 pw;
                pw.x = pkbf(p0, p1);
                pw.y = pkbf(p2, p3);
                int c = 2 * j + (quad >> 1);
                *(uint2*)(Ps + ((size_t)rq * 8 + (c ^ (rq & 7))) * 8 + (quad & 1) * 4) = pw;
            }
            ls += __shfl_xor(ls, 16);
            ls += __shfl_xor(ls, 32);
            lreg[qg] = lreg[qg] * alpha + ls;
            #pragma unroll
            for (int j = 0; j < 4; ++j) {
                o[qg][j][0] *= alpha; o[qg][j][1] *= alpha;
                o[qg][j][2] *= alpha; o[qg][j][3] *= alpha;
            }
        }

        // O^T += V^T . P^T : A = Vs (rows=d, shared), B = Ps per q-group
        #pragma unroll
        for (int ks = 0; ks < 2; ++ks) {
            const int kc = ks * 4 + quad;
            short8 bp0 = *(const short8*)(Ps + ((size_t)rq0 * 8 + (kc ^ (rq0 & 7))) * 8);
            short8 bp1 = *(const short8*)(Ps + ((size_t)rq1 * 8 + (kc ^ (rq1 & 7))) * 8);
            #pragma unroll
            for (int j = 0; j < 4; ++j) {
                int rv = j * 16 + col;
                short8 av = *(const short8*)(Vs + ((size_t)rv * 8 + (kc ^ (rv & 7))) * 8);
                o[0][j] = __builtin_amdgcn_mfma_f32_16x16x32_bf16(av, bp0, o[0][j], 0, 0, 0);
                o[1][j] = __builtin_amdgcn_mfma_f32_16x16x32_bf16(av, bp1, o[1][j], 0, 0, 0);
            }
        }
    }

    // epilogue: lane owns q rows s = q0 + w*32 + qg*16 + col, d = j*16+quad*4+r
    #pragma unroll
    for (int qg = 0; qg < 2; ++qg) {
        const float linv = 1.f / lreg[qg];
        const int s = q0 + w * 32 + qg * 16 + col;
        const size_t rowb = ((size_t)(b * SEQ + s)) * D_MODEL + h * HDIM;
        #pragma unroll
        for (int j = 0; j < 4; ++j) {
            uint2 pw;
            pw.x = pkbf(o[qg][j][0] * linv, o[qg][j][1] * linv);
            pw.y = pkbf(o[qg][j][2] * linv, o[qg][j][3] * linv);
            *(uint2*)(H + rowb + j * 16 + quad * 4) = pw;
        }
    }
}

extern "C" void kernel_launch(void* const* d_in, const int* in_sizes, int n_in,
                              void* d_out, int out_size, void* d_ws, size_t ws_size,
                              hipStream_t stream)
{
    (void)in_sizes; (void)n_in; (void)out_size; (void)ws_size;
    const float* x  = (const float*)d_in[0];
    const float* Wq = (const float*)d_in[1];
    const float* bq = (const float*)d_in[2];
    const float* Wk = (const float*)d_in[3];
    const float* bk = (const float*)d_in[4];
    const float* Wv = (const float*)d_in[5];
    const float* bv = (const float*)d_in[6];
    const float* Wo = (const float*)d_in[7];
    const float* bo = (const float*)d_in[8];

    const size_t E = (size_t)MROWS * D_MODEL;
    ushort_t* xb    = (ushort_t*)d_ws;               // [4096][1024] bf16
    ushort_t* WtQKV = xb + E;                        // [3072][1024] bf16
    ushort_t* WtO   = WtQKV + 3 * (size_t)D_MODEL * KDIM;
    ushort_t* Qb    = WtO + (size_t)D_MODEL * KDIM;  // [b,h,s,d] bf16 (pre-scaled)
    ushort_t* Kb    = Qb + E;                        // [b,h,s,d] bf16
    ushort_t* Vb    = Kb + E;                        // [b,h,d,s] bf16 (transposed)
    ushort_t* Hb    = Vb + E;                        // [4096][1024] bf16

    cvt_all<<<dim3(32, 32, 5), 256, 0, stream>>>(x, Wq, Wk, Wv, Wo, xb, WtQKV, WtO);
    gemm_mfma<128><<<dim3(24, 32), 256, 0, stream>>>(xb, WtQKV, bq, bk, bv,
                                                     nullptr, Qb, Kb, Vb, 1);
    attn_mfma<<<dim3(1024), 128, 0, stream>>>(Qb, Kb, Vb, Hb);
    gemm_mfma<64><<<dim3(16, 32), 256, 0, stream>>>(Hb, WtO, bo, nullptr, nullptr,
                                                    (float*)d_out, nullptr, nullptr, nullptr, 0);
}